// Round 6
// baseline (248.571 us; speedup 1.0000x reference)
//
#include <hip/hip_runtime.h>

// LSTM_WP: B=4096 batch-1 LSTMs, T=H=128, input_size=1, fused MFMA-f16 recurrence.
// Round 6: two-team ANTI-PHASE inside each block. r5 proved independent blocks
// convoy (occupancy doubled, zero overlap gain). Fix: 256 blocks x 16 batches,
// 8 waves = team A (waves 0-3, batches 0-7) + team B (waves 4-7, batches 8-15).
// Per t: [X: A=MFMA(t), B=elementwise(t-1)] barrier [Y: A=ew(t), B=MFMA(t)] barrier.
// Every interval pairs one MFMA wave with one trans/VALU wave per SIMD (m114
// pipe concurrency, forced structurally). Each team-wave owns 32 gate-cols
// (2 tiles, 128 VGPR weights); M=16 tile rows duplicated (row m = batch m&7),
// ew split by q so each (batch,col) is updated exactly once (r5-verified).

#define H   128
#define T   128
#define BLOCK 512
#define HSTRIDE 136     // f16 per h row: 272 B -> b128-aligned
#define XSTRIDE 18      // f32 per xs row: 16 batches + 2 pad

typedef _Float16 f16x8 __attribute__((ext_vector_type(8)));
typedef float    f32x4 __attribute__((ext_vector_type(4)));

// ---- prep: W_hh f32 [512][128] -> f16 fragment-contiguous [ct][g][kc][q][l15] ----
__global__ void prep_whh_kernel(const float* __restrict__ W_hh, _Float16* __restrict__ wfrag)
{
    int idx = blockIdx.x * blockDim.x + threadIdx.x;     // 0..8191
    int l15 =  idx        & 15;
    int q   = (idx >> 4)  & 3;
    int kc  = (idx >> 6)  & 3;
    int g   = (idx >> 8)  & 3;
    int ct  = (idx >> 10) & 7;
    int n  = g * H + ct * 16 + l15;                      // gate row in [0,512)
    int k0 = kc * 32 + q * 8;
    const float* src = W_hh + (size_t)n * H + k0;
    f16x8 f;
    #pragma unroll
    for (int i = 0; i < 8; ++i) f[i] = (_Float16)src[i];
    *(f16x8*)(wfrag + (size_t)idx * 8) = f;
}

__device__ __forceinline__ float frcp(float v) { return __builtin_amdgcn_rcpf(v); }

// ---- team MFMA step: read h(t-1) from team buf [t&1], acc = preact + h @ W^T ----
#define MFMA_STEP(tt)                                                             \
    do {                                                                          \
        const _Float16* hb = &hbuf[team][(tt) & 1][0][0];                         \
        f16x8 af[4];                                                              \
        _Pragma("unroll")                                                         \
        for (int kc = 0; kc < 4; ++kc)                                            \
            af[kc] = *(const f16x8*)(hb + (l15 & 7) * HSTRIDE + kc * 32 + q * 8); \
        _Pragma("unroll")                                                         \
        for (int ctl = 0; ctl < 2; ++ctl) {                                       \
            _Pragma("unroll")                                                     \
            for (int g = 0; g < 4; ++g) {                                         \
                f32x4 iv;                                                         \
                _Pragma("unroll")                                                 \
                for (int r = 0; r < 4; ++r)                                       \
                    iv[r] = fmaf(xs[tt][xrow + ((q * 4 + r) & 7)],                \
                                 wih[ctl][g], bias[ctl][g]);                      \
                acc[ctl][g] = __builtin_amdgcn_mfma_f32_16x16x32_f16(             \
                    af[0], wf[ctl][g][0], iv, 0, 0, 0);                           \
            }                                                                     \
        }                                                                         \
        _Pragma("unroll")                                                         \
        for (int kc = 1; kc < 4; ++kc)                                            \
            _Pragma("unroll")                                                     \
            for (int ctl = 0; ctl < 2; ++ctl)                                     \
                _Pragma("unroll")                                                 \
                for (int g = 0; g < 4; ++g)                                       \
                    acc[ctl][g] = __builtin_amdgcn_mfma_f32_16x16x32_f16(         \
                        af[kc], wf[ctl][g][kc], acc[ctl][g], 0, 0, 0);            \
    } while (0)

// ---- team elementwise step for t=tt: consume acc, write h(tt) to buf [(tt+1)&1] ----
#define EW_STEP(tt)                                                               \
    do {                                                                          \
        _Float16* hw = &hbuf[team][((tt) + 1) & 1][0][0];                         \
        _Pragma("unroll")                                                         \
        for (int ctl = 0; ctl < 2; ++ctl) {                                       \
            const int jc = (ct0 + ctl) * 16 + l15;                                \
            _Pragma("unroll")                                                     \
            for (int rr = 0; rr < 2; ++rr) {                                      \
                const int r = r0 + rr;                                            \
                float ai  = acc[ctl][0][r];                                       \
                float afv = acc[ctl][1][r];                                       \
                float ag  = acc[ctl][2][r];                                       \
                float ao  = acc[ctl][3][r];                                       \
                float Ei = __expf(-ai);                                           \
                float Ef = __expf(-afv);                                          \
                float Eg = __expf(2.0f * ag);                                     \
                float u  = 1.0f + Ei;                                             \
                float v  = 1.0f + Ef;                                             \
                float w  = 1.0f + Eg;                                             \
                float wm = Eg - 1.0f;                                             \
                float uw = u * w;                                                 \
                float cn = fmaf(cst[ctl][rr], uw, wm * v) * frcp(v * uw);         \
                cst[ctl][rr] = cn;                                                \
                float Eo = __expf(-ao);                                           \
                float Ec = __expf(2.0f * cn);                                     \
                float hv = (Ec - 1.0f) * frcp((Ec + 1.0f) * (1.0f + Eo));         \
                hw[(b0 + rr) * HSTRIDE + jc] = (_Float16)hv;                      \
            }                                                                     \
        }                                                                         \
    } while (0)

__launch_bounds__(BLOCK, 2)
__global__ void lstm_fused_kernel(const float* __restrict__ x,
                                  const float* __restrict__ W_ih,
                                  const _Float16* __restrict__ wfrag,
                                  const float* __restrict__ b_ih,
                                  const float* __restrict__ b_hh,
                                  const float* __restrict__ fc_W,
                                  const float* __restrict__ fc_b,
                                  float* __restrict__ out)
{
    __shared__ __align__(16) float xs[T + 1][XSTRIDE];           // 9.3 KB
    __shared__ __align__(16) _Float16 hbuf[2][2][8][HSTRIDE];    // [team][buf][batch][col] 8.7 KB

    const int tid  = threadIdx.x;
    const int wave = tid >> 6;
    const int lane = tid & 63;
    const int l15  = lane & 15;
    const int q    = lane >> 4;         // 0..3
    const int team = wave >> 2;         // 0 = A (batches 0-7), 1 = B (batches 8-15)
    const int wt   = wave & 3;          // wave-in-team
    const int ct0  = wt * 2;            // first of this wave's 2 column tiles
    const int xrow = team * 8;          // xs batch offset for this team

    // ew row split (r5-verified): q<2 -> rows {0,1}, q>=2 -> rows {2,3}
    const int r0 = (q >> 1) * 2;
    const int b0 = (q * 4 + r0) & 7;    // batch (within team) for row r0; r0+1 -> b0+1

    // ---- stage x: 16 batches x 128 t -> xs[t][b] ----
    {
        const int t0 = tid & 127;
        const int bb = tid >> 7;        // 0..3
        const float* xb = x + (size_t)blockIdx.x * (16 * T);
        xs[t0][bb]      = xb[bb * T + t0];
        xs[t0][bb + 4]  = xb[(bb + 4) * T + t0];
        xs[t0][bb + 8]  = xb[(bb + 8) * T + t0];
        xs[t0][bb + 12] = xb[(bb + 12) * T + t0];
    }
    // h0 = 0: zero both teams' buf 0
    for (int i = tid; i < 8 * HSTRIDE; i += BLOCK) {
        (&hbuf[0][0][0][0])[i] = (_Float16)0.0f;
        (&hbuf[1][0][0][0])[i] = (_Float16)0.0f;
    }

    // ---- weights: this wave's 2 column tiles (f16 fragments, 128 VGPRs) ----
    f16x8 wf[2][4][4];
    float wih[2][4], bias[2][4];
    #pragma unroll
    for (int ctl = 0; ctl < 2; ++ctl) {
        const _Float16* wbase = wfrag + (size_t)(ct0 + ctl) * 8192;
        #pragma unroll
        for (int g = 0; g < 4; ++g) {
            const int n = g * H + (ct0 + ctl) * 16 + l15;
            wih[ctl][g]  = W_ih[n];
            bias[ctl][g] = b_ih[n] + b_hh[n];
            #pragma unroll
            for (int kc = 0; kc < 4; ++kc)
                wf[ctl][g][kc] = *(const f16x8*)(wbase + ((((g * 4 + kc) * 4 + q) * 16 + l15) * 8));
        }
    }

    float cst[2][2] = {{0.f, 0.f}, {0.f, 0.f}};   // cell state: [tile][row]
    f32x4 acc[2][4];                              // pending gate preacts: [tile][gate]

    __syncthreads();

    for (int t = 0; t < T; ++t) {
        // ---- interval X: A = MFMA(t), B = ew(t-1) ----
        if (team == 0) {
            MFMA_STEP(t);
        } else if (t > 0) {
            EW_STEP(t - 1);
        }
        __syncthreads();
        // ---- interval Y: A = ew(t), B = MFMA(t) ----
        if (team == 0) {
            EW_STEP(t);
        } else {
            MFMA_STEP(t);
        }
        __syncthreads();
    }
    // B's last elementwise step
    if (team == 1) {
        EW_STEP(T - 1);
    }
    __syncthreads();

    // ---- epilogue: out[b] = fc_b + sum_j fc_W[j] * hT[b][j]; hT in hbuf[*][0] ----
    if (tid < 256) {
        const int b    = tid >> 4;      // 0..15
        const int part = tid & 15;
        const _Float16* hrow = &hbuf[b >> 3][0][b & 7][0];
        float s = 0.0f;
        #pragma unroll
        for (int i = 0; i < 8; ++i) {
            const int j = part * 8 + i;
            s += fc_W[j] * (float)hrow[j];
        }
        s += __shfl_xor(s, 8, 16);
        s += __shfl_xor(s, 4, 16);
        s += __shfl_xor(s, 2, 16);
        s += __shfl_xor(s, 1, 16);
        if (part == 0)
            out[blockIdx.x * 16 + b] = s + fc_b[0];
    }
}

extern "C" void kernel_launch(void* const* d_in, const int* in_sizes, int n_in,
                              void* d_out, int out_size, void* d_ws, size_t ws_size,
                              hipStream_t stream)
{
    const float* x    = (const float*)d_in[0];
    const float* W_ih = (const float*)d_in[1];
    const float* W_hh = (const float*)d_in[2];
    const float* b_ih = (const float*)d_in[3];
    const float* b_hh = (const float*)d_in[4];
    const float* fc_W = (const float*)d_in[5];
    const float* fc_b = (const float*)d_in[6];
    float* out = (float*)d_out;

    _Float16* wfrag = (_Float16*)d_ws;     // 64K f16 = 128 KB fragment-ordered W_hh

    hipLaunchKernelGGL(prep_whh_kernel, dim3(32), dim3(256), 0, stream, W_hh, wfrag);

    const int B = in_sizes[0] / H;         // 4096 chunks
    dim3 grid(B / 16);                     // 256 blocks -> 1 per CU
    dim3 block(BLOCK);                     // 8 waves: team A = 0-3, team B = 4-7
    hipLaunchKernelGGL(lstm_fused_kernel, grid, block, 0, stream,
                       x, W_ih, wfrag, b_ih, b_hh, fc_W, fc_b, out);
}

// Round 7
// 231.719 us; speedup vs baseline: 1.0727x; 1.0727x over previous
//
#include <hip/hip_runtime.h>

// LSTM_WP: B=4096 batch-1 LSTMs, T=H=128, input_size=1, fused MFMA-f16 recurrence.
// Round 7: DUAL-COHORT stagger *within each wave*. r5/r6 proved cross-wave
// anti-phasing convoys; within-wave ILP is structurally guaranteed (s_barrier
// does not wait on MFMA completion; only dependent reads do). Block = 16
// batches: cohort A = 0-7, cohort B = 8-15, B lags half an iteration:
//   [ MFMA_A(t) || ew_B(t-1) ] barrier [ MFMA_B(t) || ew_A(t) ] barrier
// Each wave issues 16 MFMAs for one cohort then independent ew VALU/trans for
// the other -> matrix pipe stays saturated, ew hides in its shadow.
// M=16 tile rows duplicated over 8 batches (row m = batch m&7, r5-verified);
// ew row-split by quad covers each (batch,col) exactly once.
// Weights pre-scaled by log2(e) (gate g by 2*log2e) -> raw exp2 activations.

#define H   128
#define T   128
#define BLOCK 512
#define HSTRIDE 136     // f16 per h row: 272 B -> b128-aligned
#define XSTRIDE 18      // f32 per xs row (16 batches + 2 pad)
#define LOG2E  1.44269504088896340736f
#define TWOLOG2E 2.88539008177792681472f

typedef _Float16 f16x8 __attribute__((ext_vector_type(8)));
typedef float    f32x4 __attribute__((ext_vector_type(4)));

// ---- prep: W_hh f32 [512][128] -> f16 fragment-contiguous, pre-scaled by log2e ----
// layout: idx(ct,g,kc,q,l15) = (((ct*4+g)*4+kc)*4+q)*16+l15, 8 f16 each (16 B).
// gates i,f,o scaled by log2e (sigmoid via exp2); gate g (index 2) by 2*log2e (tanh via exp2).
__global__ void prep_whh_kernel(const float* __restrict__ W_hh, _Float16* __restrict__ wfrag)
{
    int idx = blockIdx.x * blockDim.x + threadIdx.x;     // 0..8191
    int l15 =  idx        & 15;
    int q   = (idx >> 4)  & 3;
    int kc  = (idx >> 6)  & 3;
    int g   = (idx >> 8)  & 3;
    int ct  = (idx >> 10) & 7;
    int n  = g * H + ct * 16 + l15;                      // gate row in [0,512)
    int k0 = kc * 32 + q * 8;
    float s = (g == 2) ? TWOLOG2E : LOG2E;
    const float* src = W_hh + (size_t)n * H + k0;
    f16x8 f;
    #pragma unroll
    for (int i = 0; i < 8; ++i) f[i] = (_Float16)(src[i] * s);
    *(f16x8*)(wfrag + (size_t)idx * 8) = f;
}

__device__ __forceinline__ float frcp(float v)  { return __builtin_amdgcn_rcpf(v); }
__device__ __forceinline__ float fexp2(float v) { return __builtin_amdgcn_exp2f(v); }

// ---- one cohort's MFMA step: acc = preact(t) + h_coh @ W^T (16 MFMAs, kc-outer) ----
#define MFMA_COH(acc_, hb_, xoff_, tt_)                                           \
    do {                                                                          \
        f16x8 af[4];                                                              \
        _Pragma("unroll")                                                         \
        for (int kc = 0; kc < 4; ++kc)                                            \
            af[kc] = *(const f16x8*)((hb_) + (l15 & 7) * HSTRIDE + kc * 32 + q * 8); \
        _Pragma("unroll")                                                         \
        for (int g = 0; g < 4; ++g) {                                             \
            f32x4 iv;                                                             \
            _Pragma("unroll")                                                     \
            for (int r = 0; r < 4; ++r)                                           \
                iv[r] = fmaf(xs[tt_][(xoff_) + ((q * 4 + r) & 7)], wihs[g], biass[g]); \
            acc_[g] = __builtin_amdgcn_mfma_f32_16x16x32_f16(af[0], wf[g][0], iv, 0, 0, 0); \
        }                                                                         \
        _Pragma("unroll")                                                         \
        for (int kc = 1; kc < 4; ++kc)                                            \
            _Pragma("unroll")                                                     \
            for (int g = 0; g < 4; ++g)                                           \
                acc_[g] = __builtin_amdgcn_mfma_f32_16x16x32_f16(af[kc], wf[g][kc], acc_[g], 0, 0, 0); \
    } while (0)

// ---- one cohort's elementwise: consume acc, update c, write h (2 rows/lane) ----
// preacts already in log2 domain: sigmoid = 1/(1+2^-a); tanh = (2^a'-1)/(2^a'+1).
#define EW_COH(acc_, cst_, hb_)                                                   \
    do {                                                                          \
        _Pragma("unroll")                                                         \
        for (int rr = 0; rr < 2; ++rr) {                                          \
            const int r = r0 + rr;                                                \
            float ai  = acc_[0][r];                                               \
            float afv = acc_[1][r];                                               \
            float ag  = acc_[2][r];                                               \
            float ao  = acc_[3][r];                                               \
            float Ei = fexp2(-ai);                                                \
            float Ef = fexp2(-afv);                                               \
            float Eg = fexp2(ag);                                                 \
            float u  = 1.0f + Ei;                                                 \
            float v  = 1.0f + Ef;                                                 \
            float w  = 1.0f + Eg;                                                 \
            float wm = Eg - 1.0f;                                                 \
            float uw = u * w;                                                     \
            float cn = fmaf(cst_[rr], uw, wm * v) * frcp(v * uw);                 \
            cst_[rr] = cn;                                                        \
            float Eo = fexp2(-ao);                                                \
            float Ec = fexp2(cn * TWOLOG2E);                                      \
            float hv = (Ec - 1.0f) * frcp((Ec + 1.0f) * (1.0f + Eo));             \
            (hb_)[(b0 + rr) * HSTRIDE + jcol] = (_Float16)hv;                     \
        }                                                                         \
    } while (0)

__launch_bounds__(BLOCK, 2)
__global__ void lstm_fused_kernel(const float* __restrict__ x,
                                  const float* __restrict__ W_ih,
                                  const _Float16* __restrict__ wfrag,
                                  const float* __restrict__ b_ih,
                                  const float* __restrict__ b_hh,
                                  const float* __restrict__ fc_W,
                                  const float* __restrict__ fc_b,
                                  float* __restrict__ out)
{
    __shared__ __align__(16) float xs[T][XSTRIDE];               // 9.2 KB
    __shared__ __align__(16) _Float16 hA[8 * HSTRIDE];           // cohort A h (single buf)
    __shared__ __align__(16) _Float16 hB[8 * HSTRIDE];           // cohort B h (single buf)

    const int tid  = threadIdx.x;
    const int wave = tid >> 6;          // column tile 0..7
    const int lane = tid & 63;
    const int l15  = lane & 15;
    const int q    = lane >> 4;         // 0..3
    const int jcol = wave * 16 + l15;   // hidden column 0..127

    // ew row split (r5-verified): q<2 -> rows {0,1}, q>=2 -> rows {2,3}; batch=(q*4+r)&7
    const int r0 = (q >> 1) * 2;
    const int b0 = (q * 4 + r0) & 7;

    // ---- stage x: 16 batches x 128 t -> xs[t][b] ----
    {
        const int t0 = tid & 127;
        const int bb = tid >> 7;        // 0..3
        const float* xb = x + (size_t)blockIdx.x * (16 * T);
        xs[t0][bb]      = xb[bb * T + t0];
        xs[t0][bb + 4]  = xb[(bb + 4) * T + t0];
        xs[t0][bb + 8]  = xb[(bb + 8) * T + t0];
        xs[t0][bb + 12] = xb[(bb + 12) * T + t0];
    }
    for (int i = tid; i < 8 * HSTRIDE; i += BLOCK) {             // h0 = 0 both cohorts
        hA[i] = (_Float16)0.0f;
        hB[i] = (_Float16)0.0f;
    }

    // ---- weights: this wave's 16 gate-cols, f16 fragments (64 VGPRs) ----
    f16x8 wf[4][4];
    float wihs[4], biass[4];
    {
        const _Float16* wbase = wfrag + (size_t)wave * 8192;
        #pragma unroll
        for (int g = 0; g < 4; ++g) {
            const int n = g * H + jcol;
            const float s = (g == 2) ? TWOLOG2E : LOG2E;
            wihs[g]  = W_ih[n] * s;
            biass[g] = (b_ih[n] + b_hh[n]) * s;
            #pragma unroll
            for (int kc = 0; kc < 4; ++kc)
                wf[g][kc] = *(const f16x8*)(wbase + ((((g * 4 + kc) * 4 + q) * 16 + l15) * 8));
        }
    }

    float cA[2] = {0.f, 0.f}, cB[2] = {0.f, 0.f};
    f32x4 accA[4], accB[4];

    __syncthreads();

    // ---- prologue: start the pipeline (B lags half an iteration) ----
    MFMA_COH(accA, hA, 0, 0);           // A step 0 (h=0)
    __syncthreads();
    MFMA_COH(accB, hB, 8, 0);           // B step 0 (h=0)
    EW_COH(accA, cA, hA);               // A ew 0 -> hA(0)
    __syncthreads();

    for (int t = 1; t < T; ++t) {
        MFMA_COH(accA, hA, 0, t);       // A matmul(t)  [matrix pipe]
        EW_COH(accB, cB, hB);           // B ew(t-1)    [VALU, independent -> overlaps]
        __syncthreads();
        MFMA_COH(accB, hB, 8, t);       // B matmul(t)
        EW_COH(accA, cA, hA);           // A ew(t)
        __syncthreads();
    }
    EW_COH(accB, cB, hB);               // B ew(T-1)
    __syncthreads();

    // ---- epilogue: out[b] = fc_b + sum_j fc_W[j] * hT[b][j] ----
    if (tid < 256) {
        const int b    = tid >> 4;      // 0..15
        const int part = tid & 15;
        const _Float16* hrow = (b < 8) ? &hA[b * HSTRIDE] : &hB[(b - 8) * HSTRIDE];
        float s = 0.0f;
        #pragma unroll
        for (int i = 0; i < 8; ++i) {
            const int j = part * 8 + i;
            s += fc_W[j] * (float)hrow[j];
        }
        s += __shfl_xor(s, 8, 16);
        s += __shfl_xor(s, 4, 16);
        s += __shfl_xor(s, 2, 16);
        s += __shfl_xor(s, 1, 16);
        if (part == 0)
            out[blockIdx.x * 16 + b] = s + fc_b[0];
    }
}

extern "C" void kernel_launch(void* const* d_in, const int* in_sizes, int n_in,
                              void* d_out, int out_size, void* d_ws, size_t ws_size,
                              hipStream_t stream)
{
    const float* x    = (const float*)d_in[0];
    const float* W_ih = (const float*)d_in[1];
    const float* W_hh = (const float*)d_in[2];
    const float* b_ih = (const float*)d_in[3];
    const float* b_hh = (const float*)d_in[4];
    const float* fc_W = (const float*)d_in[5];
    const float* fc_b = (const float*)d_in[6];
    float* out = (float*)d_out;

    _Float16* wfrag = (_Float16*)d_ws;     // 64K f16 = 128 KB fragment-ordered, log2e-scaled

    hipLaunchKernelGGL(prep_whh_kernel, dim3(32), dim3(256), 0, stream, W_hh, wfrag);

    const int B = in_sizes[0] / H;         // 4096 chunks
    dim3 grid(B / 16);                     // 256 blocks -> 1 per CU
    dim3 block(BLOCK);                     // 8 waves, 2 per SIMD
    hipLaunchKernelGGL(lstm_fused_kernel, grid, block, 0, stream,
                       x, W_ih, wfrag, b_ih, b_hh, fc_W, fc_b, out);
}

// Round 8
// 168.816 us; speedup vs baseline: 1.4724x; 1.3726x over previous
//
#include <hip/hip_runtime.h>

// LSTM_WP: B=4096 batch-1 LSTMs, T=H=128, input_size=1, fused MFMA-f16 recurrence.
// Round 8: r3 structure rebuilt tight, ZERO MFMA duplication (r2/r5/r6/r7 all
// proved the duplication tax exceeds any overlap gain). 256 blocks x 16 batches,
// 8 waves, wave = 16 gate-cols, 16 MFMAs/wave/step, 1 barrier/step.
// Cuts vs r3: (1) t-loop unrolled x2 over two distinct LDS buffers -> all
// compile-time offsets, no rb/wb math; (2) log2e folded into weights/bias at
// prep (gate g x2log2e) -> raw v_exp_f32, neg via input modifier; (3) ew issues
// all 16 independent exps first, then algebra, then 4 dependent tanh(c) exps;
// (4) xs via incremented pointer, one b128/step; (5) fused-rcp c/h updates.

#define H   128
#define T   128
#define BLOCK 512
#define HSTRIDE 136     // f16 per h row: 272 B -> b128-aligned
#define XSTRIDE 20      // f32 per xs row: 80 B, b128-aligned float4 reads
#define LOG2E    1.44269504088896340736f
#define TWOLOG2E 2.88539008177792681472f

typedef _Float16 f16x8 __attribute__((ext_vector_type(8)));
typedef float    f32x4 __attribute__((ext_vector_type(4)));

// ---- prep: W_hh f32 [512][128] -> f16 fragment-contiguous, log2e-pre-scaled ----
// layout: idx(ct,g,kc,q,l15) = (((ct*4+g)*4+kc)*4+q)*16+l15, 8 f16 each (16 B).
__global__ void prep_whh_kernel(const float* __restrict__ W_hh, _Float16* __restrict__ wfrag)
{
    int idx = blockIdx.x * blockDim.x + threadIdx.x;     // 0..8191
    int l15 =  idx        & 15;
    int q   = (idx >> 4)  & 3;
    int kc  = (idx >> 6)  & 3;
    int g   = (idx >> 8)  & 3;
    int ct  = (idx >> 10) & 7;
    int n  = g * H + ct * 16 + l15;                      // gate row in [0,512)
    int k0 = kc * 32 + q * 8;
    float s = (g == 2) ? TWOLOG2E : LOG2E;
    const float* src = W_hh + (size_t)n * H + k0;
    f16x8 f;
    #pragma unroll
    for (int i = 0; i < 8; ++i) f[i] = (_Float16)(src[i] * s);
    *(f16x8*)(wfrag + (size_t)idx * 8) = f;
}

__device__ __forceinline__ float frcp(float v)  { return __builtin_amdgcn_rcpf(v); }
__device__ __forceinline__ float fexp2(float v) { return __builtin_amdgcn_exp2f(v); }

// ---- one full LSTM step for 16 batches x this wave's 16 cols ----
// hr: read h(t-1) buffer; hw: write h(t) buffer (both LDS, compile-time bases).
__device__ __forceinline__ void lstm_step(const _Float16* hr, _Float16* hw,
                                          const float* xp,
                                          const f16x8 wf[4][4],
                                          const float* wihs, const float* biass,
                                          float* c, int l15, int q, int jcol)
{
    // A-fragments: m(batch)=l15, k = kc*32 + q*8 + i (4x ds_read_b128, imm offsets)
    const _Float16* ar = hr + l15 * HSTRIDE + q * 8;
    f16x8 af0 = *(const f16x8*)(ar);
    f16x8 af1 = *(const f16x8*)(ar + 32);
    f16x8 af2 = *(const f16x8*)(ar + 64);
    f16x8 af3 = *(const f16x8*)(ar + 96);

    // preacts (log2 domain): x*W_ih + b, rows b = q*4+r (one b128 xs read)
    float4 xl = *(const float4*)xp;
    f32x4 acc[4];
    #pragma unroll
    for (int g = 0; g < 4; ++g) {
        f32x4 iv;
        iv[0] = fmaf(xl.x, wihs[g], biass[g]);
        iv[1] = fmaf(xl.y, wihs[g], biass[g]);
        iv[2] = fmaf(xl.z, wihs[g], biass[g]);
        iv[3] = fmaf(xl.w, wihs[g], biass[g]);
        acc[g] = __builtin_amdgcn_mfma_f32_16x16x32_f16(af0, wf[g][0], iv, 0, 0, 0);
    }
    #pragma unroll
    for (int g = 0; g < 4; ++g)
        acc[g] = __builtin_amdgcn_mfma_f32_16x16x32_f16(af1, wf[g][1], acc[g], 0, 0, 0);
    #pragma unroll
    for (int g = 0; g < 4; ++g)
        acc[g] = __builtin_amdgcn_mfma_f32_16x16x32_f16(af2, wf[g][2], acc[g], 0, 0, 0);
    #pragma unroll
    for (int g = 0; g < 4; ++g)
        acc[g] = __builtin_amdgcn_mfma_f32_16x16x32_f16(af3, wf[g][3], acc[g], 0, 0, 0);

    // ---- elementwise: phase 1 = all 16 independent exps (saturate trans pipe) ----
    float Ei[4], Ef[4], Eg[4], Eo[4];
    #pragma unroll
    for (int r = 0; r < 4; ++r) {
        Ei[r] = fexp2(-acc[0][r]);       // sigmoid_i = 1/(1+Ei)
        Ef[r] = fexp2(-acc[1][r]);       // sigmoid_f = 1/(1+Ef)
        Eg[r] = fexp2( acc[2][r]);       // tanh_g    = (Eg-1)/(Eg+1)
        Eo[r] = fexp2(-acc[3][r]);       // sigmoid_o = 1/(1+Eo)
    }
    // ---- phase 2: fused-rcp c/h updates + dependent tanh(c) exps ----
    _Float16* hwp = hw + (q * 4) * HSTRIDE + jcol;
    #pragma unroll
    for (int r = 0; r < 4; ++r) {
        float u  = 1.0f + Ei[r];
        float v  = 1.0f + Ef[r];
        float w  = 1.0f + Eg[r];
        float wm = Eg[r] - 1.0f;
        float uw = u * w;
        // c' = c/v + wm/(u*w) = [c*u*w + wm*v] / (v*u*w), one rcp
        float cn = fmaf(c[r], uw, wm * v) * frcp(v * uw);
        c[r] = cn;
        float Ec = fexp2(cn * TWOLOG2E); // tanh(c') = (Ec-1)/(Ec+1)
        float hv = (Ec - 1.0f) * frcp((Ec + 1.0f) * (1.0f + Eo[r]));
        hwp[r * HSTRIDE] = (_Float16)hv;
    }
}

__launch_bounds__(BLOCK, 2)
__global__ void lstm_fused_kernel(const float* __restrict__ x,
                                  const float* __restrict__ W_ih,
                                  const _Float16* __restrict__ wfrag,
                                  const float* __restrict__ b_ih,
                                  const float* __restrict__ b_hh,
                                  const float* __restrict__ fc_W,
                                  const float* __restrict__ fc_b,
                                  float* __restrict__ out)
{
    __shared__ __align__(16) float xs[T][XSTRIDE];               // 10 KB
    __shared__ __align__(16) _Float16 hb0[16 * HSTRIDE];         // h buffers (4.25 KB each)
    __shared__ __align__(16) _Float16 hb1[16 * HSTRIDE];

    const int tid  = threadIdx.x;
    const int wave = tid >> 6;          // column tile 0..7
    const int lane = tid & 63;
    const int l15  = lane & 15;
    const int q    = lane >> 4;         // 0..3
    const int jcol = wave * 16 + l15;   // hidden column 0..127

    // ---- stage x: [b][t] global -> xs[t][b] (16 batches x 128 t) ----
    {
        const int t0 = tid & 127;
        const int bb = tid >> 7;        // 0..3
        const float* xb = x + (size_t)blockIdx.x * (16 * T);
        xs[t0][bb]      = xb[bb * T + t0];
        xs[t0][bb + 4]  = xb[(bb + 4) * T + t0];
        xs[t0][bb + 8]  = xb[(bb + 8) * T + t0];
        xs[t0][bb + 12] = xb[(bb + 12) * T + t0];
    }
    for (int i = tid; i < 16 * HSTRIDE; i += BLOCK)              // h0 = 0
        hb0[i] = (_Float16)0.0f;

    // ---- weights: this wave's 16 gate-cols as f16 fragments (64 VGPRs) ----
    f16x8 wf[4][4];
    float wihs[4], biass[4];
    {
        const _Float16* wbase = wfrag + (size_t)wave * 8192;
        #pragma unroll
        for (int g = 0; g < 4; ++g) {
            const int n = g * H + jcol;
            const float s = (g == 2) ? TWOLOG2E : LOG2E;
            wihs[g]  = W_ih[n] * s;
            biass[g] = (b_ih[n] + b_hh[n]) * s;
            #pragma unroll
            for (int kc = 0; kc < 4; ++kc)
                wf[g][kc] = *(const f16x8*)(wbase + ((((g * 4 + kc) * 4 + q) * 16 + l15) * 8));
        }
    }

    float c[4] = {0.f, 0.f, 0.f, 0.f};
    const float* xp = &xs[0][q * 4];

    __syncthreads();

    // ---- recurrence: unrolled x2, compile-time buffer bases, 1 barrier/step ----
    #pragma unroll 1
    for (int t2 = 0; t2 < T / 2; ++t2) {
        lstm_step(hb0, hb1, xp, wf, wihs, biass, c, l15, q, jcol);
        xp += XSTRIDE;
        __syncthreads();
        lstm_step(hb1, hb0, xp, wf, wihs, biass, c, l15, q, jcol);
        xp += XSTRIDE;
        __syncthreads();
    }
    // T even -> final h lives in hb0

    // ---- epilogue: out[b] = fc_b + sum_j fc_W[j] * hT[b][j] ----
    if (tid < 256) {
        const int b    = tid >> 4;      // 0..15
        const int part = tid & 15;
        const _Float16* hrow = &hb0[b * HSTRIDE];
        float s = 0.0f;
        #pragma unroll
        for (int i = 0; i < 8; ++i) {
            const int j = part * 8 + i;
            s += fc_W[j] * (float)hrow[j];
        }
        s += __shfl_xor(s, 8, 16);
        s += __shfl_xor(s, 4, 16);
        s += __shfl_xor(s, 2, 16);
        s += __shfl_xor(s, 1, 16);
        if (part == 0)
            out[blockIdx.x * 16 + b] = s + fc_b[0];
    }
}

extern "C" void kernel_launch(void* const* d_in, const int* in_sizes, int n_in,
                              void* d_out, int out_size, void* d_ws, size_t ws_size,
                              hipStream_t stream)
{
    const float* x    = (const float*)d_in[0];
    const float* W_ih = (const float*)d_in[1];
    const float* W_hh = (const float*)d_in[2];
    const float* b_ih = (const float*)d_in[3];
    const float* b_hh = (const float*)d_in[4];
    const float* fc_W = (const float*)d_in[5];
    const float* fc_b = (const float*)d_in[6];
    float* out = (float*)d_out;

    _Float16* wfrag = (_Float16*)d_ws;     // 64K f16 = 128 KB fragment-ordered, log2e-scaled

    hipLaunchKernelGGL(prep_whh_kernel, dim3(32), dim3(256), 0, stream, W_hh, wfrag);

    const int B = in_sizes[0] / H;         // 4096 chunks
    dim3 grid(B / 16);                     // 256 blocks -> 1 per CU
    dim3 block(BLOCK);                     // 8 waves, 2 per SIMD
    hipLaunchKernelGGL(lstm_fused_kernel, grid, block, 0, stream,
                       x, W_ih, wfrag, b_ih, b_hh, fc_W, fc_b, out);
}